// Round 4
// baseline (491.020 us; speedup 1.0000x reference)
//
#include <hip/hip_runtime.h>

// GAT 2-layer forward on MI355X.
// Round 14: kill the grid-starved bucket_rp_sort (391 blocks, 1.5/CU, ~50us)
// and the bucket_hist full-edge pass. Insight: bucket counts are segment sums
// of node counts (bscan[b] == rp[b*256]), so:
//  - node_hist: per-node global atomics into 400KB L2-resident ncnt.
//  - 3-dispatch scan of ncnt -> rp; scan_add_init also emits ncur (per-node
//    cursors) and gcur (per-bucket cursors = rp[b*256]).
//  - chunk_scatter_sorted: unchanged LDS counting sort, but also emits u16
//    bucket ids (tmpb) alongside tmp.
//  - csr_scatter (new, 3227 blocks grid-stride): pos=atomicAdd(ncur[node]);
//    csr[pos]=s. tmp is bucket-grouped -> writes land in ~34KB windows
//    (write-amp ~1, unlike r12's unwindowed direct scatter).
// gemm1f / agg1_gemm2 / agg2_fused byte-identical to r13 for attribution.

#define DEVFN __device__ __forceinline__
#define CB_SHIFT 8
#define CB_SZ 256
#define SC_CHUNK 4096
#define NBMAX 512    // max buckets supported (N <= 131072)
#define A2B 240      // agg2 active threads per block (12 nodes x 20)

DEVFN unsigned short f2h(float f) {
  _Float16 h = (_Float16)f;
  unsigned short u;
  __builtin_memcpy(&u, &h, 2);
  return u;
}
DEVFN float h2f(unsigned short u) {
  _Float16 h;
  __builtin_memcpy(&h, &u, 2);
  return (float)h;
}

DEVFN float lrelu(float e) { return e > 0.f ? e : 0.2f * e; }

DEVFN void acc8(float* acc, float x, uint4 u) {
  acc[0] = fmaf(x, h2f(u.x & 0xffff), acc[0]);
  acc[1] = fmaf(x, h2f(u.x >> 16),    acc[1]);
  acc[2] = fmaf(x, h2f(u.y & 0xffff), acc[2]);
  acc[3] = fmaf(x, h2f(u.y >> 16),    acc[3]);
  acc[4] = fmaf(x, h2f(u.z & 0xffff), acc[4]);
  acc[5] = fmaf(x, h2f(u.z >> 16),    acc[5]);
  acc[6] = fmaf(x, h2f(u.w & 0xffff), acc[6]);
  acc[7] = fmaf(x, h2f(u.w >> 16),    acc[7]);
}

DEVFN void read_edge(const long long* eg64, const int* eg32, int is64, int E,
                     int i, int& s, int& d) {
  if (i >= E) { s = d = i - E; return; }
  if (is64) { s = (int)eg64[i]; d = (int)eg64[E + i]; }
  else      { s = eg32[i];      d = eg32[E + i]; }
}

// block-uniform edge dtype detection: EVERY wave samples the same 64 in-range
// indices (int64 data => high words all zero; int32 data => random src values).
DEVFN int detect64(const int* eg32, int E, int i0, int t) {
  int base = i0;
  if (base > E - 64) base = E - 64;
  if (base < 0) base = 0;
  int i = base + (t & 63);
  unsigned long long m = __ballot((i < E) && (eg32[2 * i + 1] != 0));
  return m == 0ull;
}

// ---------------- CSR build, stage 1: per-node degree histogram -------------
__global__ __launch_bounds__(256) void node_hist(const long long* eg64,
                                                 const int* eg32,
                                                 int E, int N,
                                                 int* __restrict__ ncnt) {
  int t = threadIdx.x;
  int is64 = detect64(eg32, E, 0, t);
  int EN = E + N;
  int base = (int)blockIdx.x * 1024 + t;
#pragma unroll
  for (int k = 0; k < 4; k++) {
    int i = base + k * 256;
    if (i < EN) {
      int d;
      if (i >= E) d = i - E;
      else d = is64 ? (int)eg64[E + i] : eg32[E + i];
      atomicAdd(&ncnt[d], 1);
    }
  }
}

// ---------------- generic scan (blocks of 1024) over node counts ------------
__global__ void scan_blocks(const int* __restrict__ cnt, int* __restrict__ rp,
                            int* __restrict__ bsum, int n) {
  __shared__ int buf[2][1024];
  int t = threadIdx.x;
  int gid = blockIdx.x * 1024 + t;
  int v = (gid < n) ? cnt[gid] : 0;
  buf[0][t] = v;
  __syncthreads();
  int pin = 0;
  for (int offd = 1; offd < 1024; offd <<= 1) {
    int nv = buf[pin][t];
    if (t >= offd) nv += buf[pin][t - offd];
    buf[1 - pin][t] = nv;
    pin = 1 - pin;
    __syncthreads();
  }
  int inc = buf[pin][t];
  if (gid < n) rp[gid] = inc - v;  // exclusive within block
  if (t == 1023) bsum[blockIdx.x] = inc;
}

// single-block parallel scan over block sums (chunked with carry, nb arbitrary)
__global__ void scan_sums(const int* __restrict__ bsum, int* __restrict__ boff,
                          int nb) {
  __shared__ int buf[2][1024];
  __shared__ int carry;
  int t = threadIdx.x;
  if (t == 0) carry = 0;
  __syncthreads();
  for (int base = 0; base < nb; base += 1024) {
    int v = (base + t < nb) ? bsum[base + t] : 0;
    buf[0][t] = v;
    __syncthreads();
    int pin = 0;
    for (int off = 1; off < 1024; off <<= 1) {
      int nv = buf[pin][t];
      if (t >= off) nv += buf[pin][t - off];
      buf[1 - pin][t] = nv;
      pin = 1 - pin;
      __syncthreads();
    }
    if (base + t < nb) boff[base + t] = carry + buf[pin][t] - v;  // exclusive
    __syncthreads();
    if (t == 0) carry += buf[pin][1023];
    __syncthreads();
  }
}

// add block offsets; emit rp, per-node cursors, per-bucket cursors
__global__ void scan_add_init(int* __restrict__ rp, const int* __restrict__ boff,
                              int* __restrict__ ncur, int* __restrict__ gcur,
                              int n, int total) {
  int i = blockIdx.x * 1024 + threadIdx.x;
  if (i < n) {
    int v = rp[i] + boff[blockIdx.x];
    rp[i] = v;
    ncur[i] = v;
    if ((i & (CB_SZ - 1)) == 0) gcur[i >> CB_SHIFT] = v;
  }
  if (i == 0) rp[n] = total;
}

// stage 3: sorted scatter. Stage chunk in regs, counting-sort by bucket in
// LDS, reserve runs with one atomicAdd per (block,bucket), burst-write runs.
__global__ __launch_bounds__(256) void chunk_scatter_sorted(
    const long long* eg64, const int* eg32, int E, int N, int NB2,
    int* __restrict__ gcur, int* __restrict__ tmp,
    unsigned short* __restrict__ tmpb) {
  __shared__ int lh[NBMAX];
  __shared__ int lscan[NBMAX];
  __shared__ int lpos[NBMAX];
  __shared__ int gbase[NBMAX];
  __shared__ int sbuf[2][NBMAX];
  __shared__ int payl[SC_CHUNK];
  __shared__ unsigned short bktid[SC_CHUNK];
  int t = threadIdx.x;
  int i0 = (int)blockIdx.x * SC_CHUNK;
  int is64 = detect64(eg32, E, i0, t);
  lh[t] = 0; lh[t + 256] = 0;
  __syncthreads();
  int EN = E + N;
  int i1 = i0 + SC_CHUNK; if (i1 > EN) i1 = EN;
  int total = i1 - i0;
  // load 16 edges/thread into regs (static indexing; d=-1 marks invalid)
  int es[16], ed[16];
#pragma unroll
  for (int bb = 0; bb < 4; bb++) {
#pragma unroll
    for (int k = 0; k < 4; k++) {
      int idx = bb * 4 + k;
      int i = i0 + bb * 1024 + k * 256 + t;
      int s = 0, d = -1;
      if (i < i1) read_edge(eg64, eg32, is64, E, i, s, d);
      es[idx] = s; ed[idx] = d;
    }
  }
  // count
#pragma unroll
  for (int j = 0; j < 16; j++)
    if (ed[j] >= 0) atomicAdd(&lh[ed[j] >> CB_SHIFT], 1);
  __syncthreads();
  // exclusive scan of 512 counters (Hillis-Steele, 2 slots/thread, dbuf)
  sbuf[0][t] = lh[t]; sbuf[0][t + 256] = lh[t + 256];
  __syncthreads();
  int pin = 0;
  for (int off = 1; off < NBMAX; off <<= 1) {
    int nv0 = sbuf[pin][t] + (t >= off ? sbuf[pin][t - off] : 0);
    int nv1 = sbuf[pin][t + 256] + sbuf[pin][t + 256 - off];
    __syncthreads();
    sbuf[1 - pin][t] = nv0; sbuf[1 - pin][t + 256] = nv1;
    pin ^= 1;
    __syncthreads();
  }
  lscan[t] = sbuf[pin][t] - lh[t];
  lscan[t + 256] = sbuf[pin][t + 256] - lh[t + 256];
  lpos[t] = lscan[t]; lpos[t + 256] = lscan[t + 256];
  // reserve global runs (one atomic per non-empty bucket in this chunk)
  if (t < NB2 && lh[t]) gbase[t] = atomicAdd(&gcur[t], lh[t]);
  int t2 = t + 256;
  if (t2 < NB2 && lh[t2]) gbase[t2] = atomicAdd(&gcur[t2], lh[t2]);
  __syncthreads();
  // place into bucket-grouped LDS order
#pragma unroll
  for (int j = 0; j < 16; j++) {
    if (ed[j] >= 0) {
      int b = ed[j] >> CB_SHIFT;
      int sl = atomicAdd(&lpos[b], 1);
      payl[sl] = (es[j] << CB_SHIFT) | (ed[j] & (CB_SZ - 1));
      bktid[sl] = (unsigned short)b;
    }
  }
  __syncthreads();
  // burst-write runs: consecutive threads -> consecutive addresses per run
  for (int j = t; j < total; j += 256) {
    int b = bktid[j];
    int dstp = gbase[b] + (j - lscan[b]);
    tmp[dstp] = payl[j];
    tmpb[dstp] = (unsigned short)b;
  }
}

// stage 4: fully parallel per-node scatter. tmp is bucket-grouped, so writes
// land inside ~34KB node windows (L2-friendly; write-amp ~1).
__global__ __launch_bounds__(256) void csr_scatter(const int* __restrict__ tmp,
                                                   const unsigned short* __restrict__ tmpb,
                                                   int* __restrict__ ncur,
                                                   int* __restrict__ csr, int EN) {
  int base = (int)blockIdx.x * 1024 + threadIdx.x;
#pragma unroll
  for (int k = 0; k < 4; k++) {
    int i = base + k * 256;
    if (i < EN) {
      int e = tmp[i];
      int node = ((int)tmpb[i] << CB_SHIFT) | (e & (CB_SZ - 1));
      int pos = atomicAdd(&ncur[node], 1);
      csr[pos] = e >> CB_SHIFT;
    }
  }
}

// ---------------- fused GEMM + attn + fp16 pack, layer 1 ----------------
__global__ __launch_bounds__(256) void gemm1f(const float* __restrict__ X,
                                              const float* __restrict__ W,
                                              const float* __restrict__ att_s,
                                              const float* __restrict__ att_d,
                                              uint4* __restrict__ h1h,
                                              float* __restrict__ as1,
                                              float* __restrict__ ad1, int N) {
  __shared__ float Wl[128 * 32];
  __shared__ float Asl[32], Adl[32];
  int t = threadIdx.x;
  for (int i = t; i < 1024; i += 256)
    ((float4*)Wl)[i] = ((const float4*)W)[i];
  if (t < 32) { Asl[t] = att_s[t]; Adl[t] = att_d[t]; }
  __syncthreads();
  int n = blockIdx.x * 256 + t;
  if (n >= N) return;
  const float4* X4 = (const float4*)(X + (size_t)n * 128);
  float acc[32];
#pragma unroll
  for (int c = 0; c < 32; c++) acc[c] = 0.f;
  for (int k4 = 0; k4 < 32; k4++) {
    float4 x = X4[k4];
    const float4* w4 = (const float4*)(Wl + k4 * 128);
#pragma unroll
    for (int c4 = 0; c4 < 8; c4++) {
      float4 w0 = w4[c4], w1 = w4[8 + c4], w2 = w4[16 + c4], w3 = w4[24 + c4];
      float* A = acc + c4 * 4;
      A[0] = fmaf(x.x, w0.x, A[0]); A[1] = fmaf(x.x, w0.y, A[1]);
      A[2] = fmaf(x.x, w0.z, A[2]); A[3] = fmaf(x.x, w0.w, A[3]);
      A[0] = fmaf(x.y, w1.x, A[0]); A[1] = fmaf(x.y, w1.y, A[1]);
      A[2] = fmaf(x.y, w1.z, A[2]); A[3] = fmaf(x.y, w1.w, A[3]);
      A[0] = fmaf(x.z, w2.x, A[0]); A[1] = fmaf(x.z, w2.y, A[1]);
      A[2] = fmaf(x.z, w2.z, A[2]); A[3] = fmaf(x.z, w2.w, A[3]);
      A[0] = fmaf(x.w, w3.x, A[0]); A[1] = fmaf(x.w, w3.y, A[1]);
      A[2] = fmaf(x.w, w3.z, A[2]); A[3] = fmaf(x.w, w3.w, A[3]);
    }
  }
  float s0 = 0.f, d0 = 0.f, s1 = 0.f, d1 = 0.f;
#pragma unroll
  for (int c = 0; c < 16; c++) {
    s0 = fmaf(acc[c], Asl[c], s0);
    d0 = fmaf(acc[c], Adl[c], d0);
    s1 = fmaf(acc[16 + c], Asl[16 + c], s1);
    d1 = fmaf(acc[16 + c], Adl[16 + c], d1);
  }
  as1[n * 2] = s0; as1[n * 2 + 1] = s1;
  ad1[n * 2] = d0; ad1[n * 2 + 1] = d1;
#pragma unroll
  for (int j = 0; j < 4; j++) {
    uint4 u;
    u.x = (unsigned)f2h(acc[j * 8 + 0]) | ((unsigned)f2h(acc[j * 8 + 1]) << 16);
    u.y = (unsigned)f2h(acc[j * 8 + 2]) | ((unsigned)f2h(acc[j * 8 + 3]) << 16);
    u.z = (unsigned)f2h(acc[j * 8 + 4]) | ((unsigned)f2h(acc[j * 8 + 5]) << 16);
    u.w = (unsigned)f2h(acc[j * 8 + 6]) | ((unsigned)f2h(acc[j * 8 + 7]) << 16);
    h1h[(size_t)n * 4 + j] = u;
  }
}

// ------- fused agg1 (split-K=4, shfl) + gemm2 + attn2 + fp16 pack -----------
// block = 16 nodes x 16 threads; r=(half 0-3, cq 0-3); x1 row only in LDS.
// r11: 4-edge unrolled gather loop + predicated 3-wide batched tail.
__global__ __launch_bounds__(256, 8) void agg1_gemm2(
    const int* __restrict__ rp, const int* __restrict__ csr,
    const float* __restrict__ as, const float* __restrict__ ad,
    const uint4* __restrict__ h1h, const float* __restrict__ b1,
    const float* __restrict__ W2, const float* __restrict__ as2w,
    const float* __restrict__ ad2w, uint4* __restrict__ h2h,
    float* __restrict__ as2, float* __restrict__ ad2, int N) {
  __shared__ float Wl[32 * 40];
  __shared__ float As2l[40], Ad2l[40];
  __shared__ float x1t[16][33];
  __shared__ float h2r[16][41];
  int t = threadIdx.x;
  for (int i = t; i < 320; i += 256)
    ((float4*)Wl)[i] = ((const float4*)W2)[i];
  if (t < 40) { As2l[t] = as2w[t]; Ad2l[t] = ad2w[t]; }
  int nl = t >> 4, r = t & 15;
  int half = r >> 2, cq = r & 3;
  int h = cq >> 1;
  int n = blockIdx.x * 16 + nl;
  float acc[8] = {0, 0, 0, 0, 0, 0, 0, 0};
  float ssum = 0.f;
  if (n < N) {
    int p0 = rp[n], p1 = rp[n + 1];
    float adv = ad[n * 2 + h];
    int p = p0 + half;
    // main: 4 independent csr->gather chains in flight per iteration
    for (; p + 12 < p1; p += 16) {
      int sA = csr[p], sB = csr[p + 4], sC = csr[p + 8], sD = csr[p + 12];
      float eA = as[sA * 2 + h] + adv;
      float eB = as[sB * 2 + h] + adv;
      float eC = as[sC * 2 + h] + adv;
      float eD = as[sD * 2 + h] + adv;
      uint4 uA = h1h[(size_t)sA * 4 + cq];
      uint4 uB = h1h[(size_t)sB * 4 + cq];
      uint4 uC = h1h[(size_t)sC * 4 + cq];
      uint4 uD = h1h[(size_t)sD * 4 + cq];
      float xA = __expf(lrelu(eA));
      float xB = __expf(lrelu(eB));
      float xC = __expf(lrelu(eC));
      float xD = __expf(lrelu(eD));
      ssum += (xA + xB) + (xC + xD);
      acc8(acc, xA, uA);
      acc8(acc, xB, uB);
      acc8(acc, xC, uC);
      acc8(acc, xD, uD);
    }
    // tail: <=3 edges, one parallel memory round (clamped + predicated)
    if (p < p1) {
      bool vB = p + 4 < p1, vC = p + 8 < p1;
      int pB = vB ? p + 4 : p;
      int pC = vC ? p + 8 : p;
      int sA = csr[p], sB = csr[pB], sC = csr[pC];
      float eA = as[sA * 2 + h] + adv;
      float eB = as[sB * 2 + h] + adv;
      float eC = as[sC * 2 + h] + adv;
      uint4 uA = h1h[(size_t)sA * 4 + cq];
      uint4 uB = h1h[(size_t)sB * 4 + cq];
      uint4 uC = h1h[(size_t)sC * 4 + cq];
      float xA = __expf(lrelu(eA));
      float xB = vB ? __expf(lrelu(eB)) : 0.f;
      float xC = vC ? __expf(lrelu(eC)) : 0.f;
      ssum += xA + xB + xC;
      acc8(acc, xA, uA);
      acc8(acc, xB, uB);
      acc8(acc, xC, uC);
    }
  }
  // combine 4 split-K halves (lanes r^4, r^8 within the 16-lane node group)
#pragma unroll
  for (int j = 0; j < 8; j++) acc[j] += __shfl_xor(acc[j], 4);
  ssum += __shfl_xor(ssum, 4);
#pragma unroll
  for (int j = 0; j < 8; j++) acc[j] += __shfl_xor(acc[j], 8);
  ssum += __shfl_xor(ssum, 8);
  if (n < N && half == 0) {
    float inv = 1.0f / (ssum + 1e-16f);
    float4 ba = ((const float4*)b1)[cq * 2];
    float4 bb = ((const float4*)b1)[cq * 2 + 1];
    int ch0 = cq * 8;
    x1t[nl][ch0 + 0] = fmaxf(fmaf(acc[0], inv, ba.x), 0.f);
    x1t[nl][ch0 + 1] = fmaxf(fmaf(acc[1], inv, ba.y), 0.f);
    x1t[nl][ch0 + 2] = fmaxf(fmaf(acc[2], inv, ba.z), 0.f);
    x1t[nl][ch0 + 3] = fmaxf(fmaf(acc[3], inv, ba.w), 0.f);
    x1t[nl][ch0 + 4] = fmaxf(fmaf(acc[4], inv, bb.x), 0.f);
    x1t[nl][ch0 + 5] = fmaxf(fmaf(acc[5], inv, bb.y), 0.f);
    x1t[nl][ch0 + 6] = fmaxf(fmaf(acc[6], inv, bb.z), 0.f);
    x1t[nl][ch0 + 7] = fmaxf(fmaf(acc[7], inv, bb.w), 0.f);
  }
  __syncthreads();
  // gemm2: 8 threads/node (r<8), 5 out-channels each
  if (n < N && r < 8) {
    float acc2[5] = {0, 0, 0, 0, 0};
    int cb = r * 5;
    for (int k = 0; k < 32; k++) {
      float x = x1t[nl][k];
#pragma unroll
      for (int c = 0; c < 5; c++)
        acc2[c] = fmaf(x, Wl[k * 40 + cb + c], acc2[c]);
    }
    float ss = 0.f, sd = 0.f;
#pragma unroll
    for (int c = 0; c < 5; c++) {
      ss = fmaf(acc2[c], As2l[cb + c], ss);
      sd = fmaf(acc2[c], Ad2l[cb + c], sd);
    }
#pragma unroll
    for (int off = 1; off < 8; off <<= 1) {
      ss += __shfl_xor(ss, off);
      sd += __shfl_xor(sd, off);
    }
    if (r == 0) { as2[n] = ss; ad2[n] = sd; }
#pragma unroll
    for (int c = 0; c < 5; c++) h2r[nl][cb + c] = acc2[c];
  }
  __syncthreads();
  if (n < N && r < 5) {
    const float* hr = h2r[nl] + r * 8;
    uint4 u;
    u.x = (unsigned)f2h(hr[0]) | ((unsigned)f2h(hr[1]) << 16);
    u.y = (unsigned)f2h(hr[2]) | ((unsigned)f2h(hr[3]) << 16);
    u.z = (unsigned)f2h(hr[4]) | ((unsigned)f2h(hr[5]) << 16);
    u.w = (unsigned)f2h(hr[6]) | ((unsigned)f2h(hr[7]) << 16);
    h2h[(size_t)n * 8 + r] = u;  // 128B row stride, 80B used
  }
}

// ---------------- fused softmax+agg, layer 2 (split-K=4, LDS combine) -------
// blocks of 240 active threads (12 nodes x 20); rr = half*5 + cq, half 0-3
// r11: 4-edge unrolled gather loop + predicated 3-wide batched tail.
__global__ __launch_bounds__(256, 8) void agg2_fused(const int* __restrict__ rp,
                                                     const int* __restrict__ csr,
                                                     const float* __restrict__ as,
                                                     const float* __restrict__ ad,
                                                     const uint4* __restrict__ h2h,
                                                     const float* __restrict__ bias,
                                                     float* __restrict__ outp, int N) {
  __shared__ float part[256][9];
  int t = threadIdx.x;
  int idx = blockIdx.x * A2B + t;
  bool act = (t < A2B) && (idx < N * 20);
  int n = 0, half = 0, cq = 0, p0 = 0, p1 = 0;
  float adv = 0.f;
  if (act) {
    n = idx / 20;
    int rr = idx % 20;
    half = rr / 5;
    cq = rr - half * 5;
    p0 = rp[n]; p1 = rp[n + 1];
    adv = ad[n];
  }
  float acc[8] = {0, 0, 0, 0, 0, 0, 0, 0};
  float ssum = 0.f;
  if (act) {
    int p = p0 + half;
    for (; p + 12 < p1; p += 16) {
      int sA = csr[p], sB = csr[p + 4], sC = csr[p + 8], sD = csr[p + 12];
      float eA = as[sA] + adv;
      float eB = as[sB] + adv;
      float eC = as[sC] + adv;
      float eD = as[sD] + adv;
      uint4 uA = h2h[(size_t)sA * 8 + cq];
      uint4 uB = h2h[(size_t)sB * 8 + cq];
      uint4 uC = h2h[(size_t)sC * 8 + cq];
      uint4 uD = h2h[(size_t)sD * 8 + cq];
      float xA = __expf(lrelu(eA));
      float xB = __expf(lrelu(eB));
      float xC = __expf(lrelu(eC));
      float xD = __expf(lrelu(eD));
      ssum += (xA + xB) + (xC + xD);
      acc8(acc, xA, uA);
      acc8(acc, xB, uB);
      acc8(acc, xC, uC);
      acc8(acc, xD, uD);
    }
    if (p < p1) {
      bool vB = p + 4 < p1, vC = p + 8 < p1;
      int pB = vB ? p + 4 : p;
      int pC = vC ? p + 8 : p;
      int sA = csr[p], sB = csr[pB], sC = csr[pC];
      float eA = as[sA] + adv;
      float eB = as[sB] + adv;
      float eC = as[sC] + adv;
      uint4 uA = h2h[(size_t)sA * 8 + cq];
      uint4 uB = h2h[(size_t)sB * 8 + cq];
      uint4 uC = h2h[(size_t)sC * 8 + cq];
      float xA = __expf(lrelu(eA));
      float xB = vB ? __expf(lrelu(eB)) : 0.f;
      float xC = vC ? __expf(lrelu(eC)) : 0.f;
      ssum += xA + xB + xC;
      acc8(acc, xA, uA);
      acc8(acc, xB, uB);
      acc8(acc, xC, uC);
    }
  }
  if (act && half) {
#pragma unroll
    for (int j = 0; j < 8; j++) part[t][j] = acc[j];
    part[t][8] = ssum;
  }
  __syncthreads();
  if (act && half == 0) {
#pragma unroll
    for (int j = 0; j < 8; j++)
      acc[j] += part[t + 5][j] + part[t + 10][j] + part[t + 15][j];
    ssum += part[t + 5][8] + part[t + 10][8] + part[t + 15][8];
    float inv = 1.0f / (ssum + 1e-16f);
    const float4* b4 = (const float4*)bias;
    float4 ba = b4[cq * 2], bb = b4[cq * 2 + 1];
    float4 r0, r1;
    r0.x = fmaf(acc[0], inv, ba.x);
    r0.y = fmaf(acc[1], inv, ba.y);
    r0.z = fmaf(acc[2], inv, ba.z);
    r0.w = fmaf(acc[3], inv, ba.w);
    r1.x = fmaf(acc[4], inv, bb.x);
    r1.y = fmaf(acc[5], inv, bb.y);
    r1.z = fmaf(acc[6], inv, bb.z);
    r1.w = fmaf(acc[7], inv, bb.w);
    ((float4*)outp)[(size_t)n * 10 + cq * 2]     = r0;
    ((float4*)outp)[(size_t)n * 10 + cq * 2 + 1] = r1;
  }
}

// ---------------- host launcher ----------------
extern "C" void kernel_launch(void* const* d_in, const int* in_sizes, int n_in,
                              void* d_out, int out_size, void* d_ws, size_t ws_size,
                              hipStream_t stream) {
  const float* X    = (const float*)d_in[0];
  const long long* eg64 = (const long long*)d_in[1];
  const int* eg32   = (const int*)d_in[1];
  const float* W1   = (const float*)d_in[3];
  const float* as1w = (const float*)d_in[4];
  const float* ad1w = (const float*)d_in[5];
  const float* b1   = (const float*)d_in[6];
  const float* W2   = (const float*)d_in[7];
  const float* as2w = (const float*)d_in[8];
  const float* ad2w = (const float*)d_in[9];
  const float* b2   = (const float*)d_in[10];
  float* out = (float*)d_out;

  const int N  = in_sizes[0] / 128;
  const int E  = in_sizes[1] / 2;
  const int EN = E + N;
  const int NB2 = (N + CB_SZ - 1) / CB_SZ;
  const int NWG = (EN + SC_CHUNK - 1) / SC_CHUNK;
  const int NWE = (EN + 1023) / 1024;
  const int nbS = (N + 1023) / 1024;

  char* wbase = (char*)d_ws;
  size_t off = 0;
  auto alloc = [&](size_t bytes) -> void* {
    void* p = wbase + off;
    off += (bytes + 255) & ~(size_t)255;
    return p;
  };

  uint4* h1h = (uint4*)alloc((size_t)N * 64);        // fp16 h1, 64B rows
  // tmp (CSR build scratch) and h2h (layer-2 fp16 payload) are temporally
  // disjoint: tmp dies at csr_scatter, h2h is born at agg1_gemm2.
  size_t usz = (size_t)EN * 4;
  if ((size_t)N * 128 > usz) usz = (size_t)N * 128;
  char* uni = (char*)alloc(usz);
  uint4* h2h = (uint4*)uni;
  int*   tmp = (int*)uni;
  unsigned short* tmpb = (unsigned short*)alloc((size_t)EN * 2);
  float* as1 = (float*)alloc((size_t)N * 2 * 4);
  float* ad1 = (float*)alloc((size_t)N * 2 * 4);
  float* as2 = (float*)alloc((size_t)N * 4);
  float* ad2 = (float*)alloc((size_t)N * 4);
  int* rp     = (int*)alloc((size_t)(N + 1) * 4);
  int* ncnt   = (int*)alloc((size_t)N * 4);
  int* ncur   = (int*)alloc((size_t)N * 4);
  int* gcur   = (int*)alloc(NBMAX * 4);
  int* bsum   = (int*)alloc(1024 * 4);
  int* boff   = (int*)alloc(1024 * 4);
  int* csr    = (int*)alloc((size_t)EN * 4);
  (void)ws_size; (void)n_in; (void)out_size;

  const int gN = (N + 255) / 256;

  // CSR build: node hist -> scan(+cursor init) -> sorted scatter -> node scatter
  hipMemsetAsync(ncnt, 0, (size_t)N * 4, stream);
  node_hist<<<NWE, 256, 0, stream>>>(eg64, eg32, E, N, ncnt);
  scan_blocks<<<nbS, 1024, 0, stream>>>(ncnt, rp, bsum, N);
  scan_sums<<<1, 1024, 0, stream>>>(bsum, boff, nbS);
  scan_add_init<<<nbS, 1024, 0, stream>>>(rp, boff, ncur, gcur, N, EN);
  chunk_scatter_sorted<<<NWG, 256, 0, stream>>>(eg64, eg32, E, N, NB2, gcur,
                                                tmp, tmpb);
  csr_scatter<<<NWE, 256, 0, stream>>>(tmp, tmpb, ncur, csr, EN);

  // Layer 1 projection
  gemm1f<<<gN, 256, 0, stream>>>(X, W1, as1w, ad1w, h1h, as1, ad1, N);
  // agg1 + gemm2 + attn2 fused (x1 never touches global)
  agg1_gemm2<<<(N + 15) / 16, 256, 0, stream>>>(rp, csr, as1, ad1, h1h, b1,
                                                W2, as2w, ad2w, h2h, as2, ad2, N);
  // Layer 2 aggregation -> output
  agg2_fused<<<(N * 20 + A2B - 1) / A2B, 256, 0, stream>>>(rp, csr, as2, ad2,
                                                           h2h, b2, out, N);
}

// Round 5
// 323.262 us; speedup vs baseline: 1.5190x; 1.5190x over previous
//
#include <hip/hip_runtime.h>

// GAT 2-layer forward on MI355X.
// Round 15: (a) FULL REVERT of the CSR build to r13 (r14 lesson: per-edge
// device-scope global atomics are fabric-serialized -- node_hist hit 130us,
// WRITE 100MB for a 400KB array; only LDS-aggregated histograms are viable).
// (b) Algebraic restructure of layer 2: W2 commutes with the alpha-weighted
// segment sum, so aggregate x1 (fp16 64B rows, ONE line/edge) and apply the
// 32x40 GEMM per NODE post-aggregation; att2 scalars become dots with
// va=W2*att_src2, vb=W2*att_dst2. h2h (128B rows, 2 lines/edge, 10MB write)
// is deleted entirely; agg1's gemm2/h2r/pack epilogue dies.
// Build kernels + gemm1f byte-identical to r13 for attribution.

#define DEVFN __device__ __forceinline__
#define CB_SHIFT 8
#define CB_SZ 256
#define SC_CHUNK 4096
#define NBMAX 512    // max buckets supported (N <= 131072)
#define STASH 12288  // bucket stash entries (mean ~8.5k)

DEVFN unsigned short f2h(float f) {
  _Float16 h = (_Float16)f;
  unsigned short u;
  __builtin_memcpy(&u, &h, 2);
  return u;
}
DEVFN float h2f(unsigned short u) {
  _Float16 h;
  __builtin_memcpy(&h, &u, 2);
  return (float)h;
}

DEVFN float lrelu(float e) { return e > 0.f ? e : 0.2f * e; }

DEVFN void acc8(float* acc, float x, uint4 u) {
  acc[0] = fmaf(x, h2f(u.x & 0xffff), acc[0]);
  acc[1] = fmaf(x, h2f(u.x >> 16),    acc[1]);
  acc[2] = fmaf(x, h2f(u.y & 0xffff), acc[2]);
  acc[3] = fmaf(x, h2f(u.y >> 16),    acc[3]);
  acc[4] = fmaf(x, h2f(u.z & 0xffff), acc[4]);
  acc[5] = fmaf(x, h2f(u.z >> 16),    acc[5]);
  acc[6] = fmaf(x, h2f(u.w & 0xffff), acc[6]);
  acc[7] = fmaf(x, h2f(u.w >> 16),    acc[7]);
}

DEVFN void read_edge(const long long* eg64, const int* eg32, int is64, int E,
                     int i, int& s, int& d) {
  if (i >= E) { s = d = i - E; return; }
  if (is64) { s = (int)eg64[i]; d = (int)eg64[E + i]; }
  else      { s = eg32[i];      d = eg32[E + i]; }
}

// block-uniform edge dtype detection: EVERY wave samples the same 64 in-range
// indices (int64 data => high words all zero; int32 data => random src values).
DEVFN int detect64(const int* eg32, int E, int i0, int t) {
  int base = i0;
  if (base > E - 64) base = E - 64;
  if (base < 0) base = 0;
  int i = base + (t & 63);
  unsigned long long m = __ballot((i < E) && (eg32[2 * i + 1] != 0));
  return m == 0ull;
}

// ---------------- CSR build, stage 1: global bucket histogram ----------------
__global__ __launch_bounds__(256) void bucket_hist(const long long* eg64,
                                                   const int* eg32,
                                                   int E, int N, int NB2,
                                                   int* __restrict__ bhist) {
  __shared__ int lh[NBMAX];
  int t = threadIdx.x;
  lh[t] = 0; lh[t + 256] = 0;
  int is64 = detect64(eg32, E, 0, t);
  __syncthreads();
  int EN = E + N;
  int step = (int)gridDim.x * 1024;
  for (int base = (int)blockIdx.x * 1024; base < EN; base += step) {
#pragma unroll
    for (int k = 0; k < 4; k++) {
      int i = base + k * 256 + t;
      if (i < EN) {
        int d;
        if (i >= E) d = i - E;
        else d = is64 ? (int)eg64[E + i] : eg32[E + i];
        atomicAdd(&lh[d >> CB_SHIFT], 1);
      }
    }
  }
  __syncthreads();
  if (t < NB2 && lh[t]) atomicAdd(&bhist[t], lh[t]);
  int t2 = t + 256;
  if (t2 < NB2 && lh[t2]) atomicAdd(&bhist[t2], lh[t2]);
}

// stage 2: single-block scan over NB2 bucket counts -> bscan (excl) + gcur
__global__ void bucket_scan(const int* __restrict__ bhist,
                            int* __restrict__ bscan, int* __restrict__ gcur,
                            int NB2, int EN) {
  __shared__ int buf[2][NBMAX];
  int t = threadIdx.x;  // 512 threads
  int v = (t < NB2) ? bhist[t] : 0;
  buf[0][t] = v;
  __syncthreads();
  int pin = 0;
  for (int off = 1; off < NBMAX; off <<= 1) {
    int nv = buf[pin][t] + (t >= off ? buf[pin][t - off] : 0);
    buf[1 - pin][t] = nv;
    pin ^= 1;
    __syncthreads();
  }
  int excl = buf[pin][t] - v;
  if (t < NB2) { bscan[t] = excl; gcur[t] = excl; }
  if (t == NB2) bscan[t] = EN;
}

// stage 3: sorted scatter. Stage chunk in regs, counting-sort by bucket in
// LDS, reserve runs with one atomicAdd per (block,bucket), burst-write runs.
__global__ __launch_bounds__(256) void chunk_scatter_sorted(
    const long long* eg64, const int* eg32, int E, int N, int NB2,
    int* __restrict__ gcur, int* __restrict__ tmp) {
  __shared__ int lh[NBMAX];
  __shared__ int lscan[NBMAX];
  __shared__ int lpos[NBMAX];
  __shared__ int gbase[NBMAX];
  __shared__ int sbuf[2][NBMAX];
  __shared__ int payl[SC_CHUNK];
  __shared__ unsigned short bktid[SC_CHUNK];
  int t = threadIdx.x;
  int i0 = (int)blockIdx.x * SC_CHUNK;
  int is64 = detect64(eg32, E, i0, t);
  lh[t] = 0; lh[t + 256] = 0;
  __syncthreads();
  int EN = E + N;
  int i1 = i0 + SC_CHUNK; if (i1 > EN) i1 = EN;
  int total = i1 - i0;
  // load 16 edges/thread into regs (static indexing; d=-1 marks invalid)
  int es[16], ed[16];
#pragma unroll
  for (int bb = 0; bb < 4; bb++) {
#pragma unroll
    for (int k = 0; k < 4; k++) {
      int idx = bb * 4 + k;
      int i = i0 + bb * 1024 + k * 256 + t;
      int s = 0, d = -1;
      if (i < i1) read_edge(eg64, eg32, is64, E, i, s, d);
      es[idx] = s; ed[idx] = d;
    }
  }
  // count
#pragma unroll
  for (int j = 0; j < 16; j++)
    if (ed[j] >= 0) atomicAdd(&lh[ed[j] >> CB_SHIFT], 1);
  __syncthreads();
  // exclusive scan of 512 counters (Hillis-Steele, 2 slots/thread, dbuf)
  sbuf[0][t] = lh[t]; sbuf[0][t + 256] = lh[t + 256];
  __syncthreads();
  int pin = 0;
  for (int off = 1; off < NBMAX; off <<= 1) {
    int nv0 = sbuf[pin][t] + (t >= off ? sbuf[pin][t - off] : 0);
    int nv1 = sbuf[pin][t + 256] + sbuf[pin][t + 256 - off];
    __syncthreads();
    sbuf[1 - pin][t] = nv0; sbuf[1 - pin][t + 256] = nv1;
    pin ^= 1;
    __syncthreads();
  }
  lscan[t] = sbuf[pin][t] - lh[t];
  lscan[t + 256] = sbuf[pin][t + 256] - lh[t + 256];
  lpos[t] = lscan[t]; lpos[t + 256] = lscan[t + 256];
  // reserve global runs (one atomic per non-empty bucket in this chunk)
  if (t < NB2 && lh[t]) gbase[t] = atomicAdd(&gcur[t], lh[t]);
  int t2 = t + 256;
  if (t2 < NB2 && lh[t2]) gbase[t2] = atomicAdd(&gcur[t2], lh[t2]);
  __syncthreads();
  // place into bucket-grouped LDS order
#pragma unroll
  for (int j = 0; j < 16; j++) {
    if (ed[j] >= 0) {
      int b = ed[j] >> CB_SHIFT;
      int sl = atomicAdd(&lpos[b], 1);
      payl[sl] = (es[j] << CB_SHIFT) | (ed[j] & (CB_SZ - 1));
      bktid[sl] = (unsigned short)b;
    }
  }
  __syncthreads();
  // burst-write runs: consecutive threads -> consecutive addresses per run
  for (int j = t; j < total; j += 256) {
    int b = bktid[j];
    tmp[gbase[b] + (j - lscan[b])] = payl[j];
  }
}

// stage 4: per-bucket (256 nodes) node counts + in-LDS scan -> rp; scatter
// tmp -> csr. LDS stash avoids the global re-read in pass 2.
__global__ __launch_bounds__(256) void bucket_rp_sort(const int* __restrict__ bscan,
                                                      const int* __restrict__ tmp,
                                                      int* __restrict__ rp,
                                                      int* __restrict__ csr,
                                                      int N, int EN) {
  __shared__ int lc[CB_SZ];
  __shared__ int ps[256];
  __shared__ int lcur[CB_SZ];
  __shared__ int stash[STASH];
  int b = blockIdx.x, t = threadIdx.x;
  lc[t] = 0;
  __syncthreads();
  int w0 = bscan[b];
  int w1 = bscan[b + 1];
  int cnt = w1 - w0;
  bool fit = (cnt <= STASH);
  // pass 1: count (+stash), 4-stride MLP + predicated 3-wide tail
  int p = w0 + t;
  for (; p + 768 < w1; p += 1024) {
    int e0 = tmp[p], e1 = tmp[p + 256], e2 = tmp[p + 512], e3 = tmp[p + 768];
    if (fit) {
      stash[p - w0] = e0; stash[p - w0 + 256] = e1;
      stash[p - w0 + 512] = e2; stash[p - w0 + 768] = e3;
    }
    atomicAdd(&lc[e0 & (CB_SZ - 1)], 1);
    atomicAdd(&lc[e1 & (CB_SZ - 1)], 1);
    atomicAdd(&lc[e2 & (CB_SZ - 1)], 1);
    atomicAdd(&lc[e3 & (CB_SZ - 1)], 1);
  }
  if (p < w1) {
    bool v1 = p + 256 < w1, v2 = p + 512 < w1;
    int q1 = v1 ? p + 256 : p;
    int q2 = v2 ? p + 512 : p;
    int e0 = tmp[p], e1 = tmp[q1], e2 = tmp[q2];
    if (fit) {
      stash[p - w0] = e0;
      if (v1) stash[q1 - w0] = e1;
      if (v2) stash[q2 - w0] = e2;
    }
    atomicAdd(&lc[e0 & (CB_SZ - 1)], 1);
    if (v1) atomicAdd(&lc[e1 & (CB_SZ - 1)], 1);
    if (v2) atomicAdd(&lc[e2 & (CB_SZ - 1)], 1);
  }
  __syncthreads();
  int a = lc[t];
  ps[t] = a;
  __syncthreads();
  for (int off = 1; off < 256; off <<= 1) {
    int v = ps[t];
    int u = (t >= off) ? ps[t - off] : 0;
    __syncthreads();
    ps[t] = v + u;
    __syncthreads();
  }
  int base = w0 + ps[t] - a;  // exclusive prefix within bucket
  lcur[t] = base;
  int n0 = b * CB_SZ;
  if (n0 + t < N) rp[n0 + t] = base;
  if (b == (int)gridDim.x - 1 && t == 0) rp[N] = EN;
  __syncthreads();
  // pass 2: scatter from stash (or global fallback)
  if (fit) {
    for (int j = t; j < cnt; j += 256) {
      int e = stash[j];
      int pos = atomicAdd(&lcur[e & (CB_SZ - 1)], 1);
      csr[pos] = e >> CB_SHIFT;
    }
  } else {
    for (int q = w0 + t; q < w1; q += 256) {
      int e = tmp[q];
      int pos = atomicAdd(&lcur[e & (CB_SZ - 1)], 1);
      csr[pos] = e >> CB_SHIFT;
    }
  }
}

// ---------------- fused GEMM + attn + fp16 pack, layer 1 ----------------
__global__ __launch_bounds__(256) void gemm1f(const float* __restrict__ X,
                                              const float* __restrict__ W,
                                              const float* __restrict__ att_s,
                                              const float* __restrict__ att_d,
                                              uint4* __restrict__ h1h,
                                              float* __restrict__ as1,
                                              float* __restrict__ ad1, int N) {
  __shared__ float Wl[128 * 32];
  __shared__ float Asl[32], Adl[32];
  int t = threadIdx.x;
  for (int i = t; i < 1024; i += 256)
    ((float4*)Wl)[i] = ((const float4*)W)[i];
  if (t < 32) { Asl[t] = att_s[t]; Adl[t] = att_d[t]; }
  __syncthreads();
  int n = blockIdx.x * 256 + t;
  if (n >= N) return;
  const float4* X4 = (const float4*)(X + (size_t)n * 128);
  float acc[32];
#pragma unroll
  for (int c = 0; c < 32; c++) acc[c] = 0.f;
  for (int k4 = 0; k4 < 32; k4++) {
    float4 x = X4[k4];
    const float4* w4 = (const float4*)(Wl + k4 * 128);
#pragma unroll
    for (int c4 = 0; c4 < 8; c4++) {
      float4 w0 = w4[c4], w1 = w4[8 + c4], w2 = w4[16 + c4], w3 = w4[24 + c4];
      float* A = acc + c4 * 4;
      A[0] = fmaf(x.x, w0.x, A[0]); A[1] = fmaf(x.x, w0.y, A[1]);
      A[2] = fmaf(x.x, w0.z, A[2]); A[3] = fmaf(x.x, w0.w, A[3]);
      A[0] = fmaf(x.y, w1.x, A[0]); A[1] = fmaf(x.y, w1.y, A[1]);
      A[2] = fmaf(x.y, w1.z, A[2]); A[3] = fmaf(x.y, w1.w, A[3]);
      A[0] = fmaf(x.z, w2.x, A[0]); A[1] = fmaf(x.z, w2.y, A[1]);
      A[2] = fmaf(x.z, w2.z, A[2]); A[3] = fmaf(x.z, w2.w, A[3]);
      A[0] = fmaf(x.w, w3.x, A[0]); A[1] = fmaf(x.w, w3.y, A[1]);
      A[2] = fmaf(x.w, w3.z, A[2]); A[3] = fmaf(x.w, w3.w, A[3]);
    }
  }
  float s0 = 0.f, d0 = 0.f, s1 = 0.f, d1 = 0.f;
#pragma unroll
  for (int c = 0; c < 16; c++) {
    s0 = fmaf(acc[c], Asl[c], s0);
    d0 = fmaf(acc[c], Adl[c], d0);
    s1 = fmaf(acc[16 + c], Asl[16 + c], s1);
    d1 = fmaf(acc[16 + c], Adl[16 + c], d1);
  }
  as1[n * 2] = s0; as1[n * 2 + 1] = s1;
  ad1[n * 2] = d0; ad1[n * 2 + 1] = d1;
#pragma unroll
  for (int j = 0; j < 4; j++) {
    uint4 u;
    u.x = (unsigned)f2h(acc[j * 8 + 0]) | ((unsigned)f2h(acc[j * 8 + 1]) << 16);
    u.y = (unsigned)f2h(acc[j * 8 + 2]) | ((unsigned)f2h(acc[j * 8 + 3]) << 16);
    u.z = (unsigned)f2h(acc[j * 8 + 4]) | ((unsigned)f2h(acc[j * 8 + 5]) << 16);
    u.w = (unsigned)f2h(acc[j * 8 + 6]) | ((unsigned)f2h(acc[j * 8 + 7]) << 16);
    h1h[(size_t)n * 4 + j] = u;
  }
}

// ------- fused agg1 (split-K=4, shfl) + x1 fp16 pack + attn2 dots -----------
// block = 16 nodes x 16 threads; r=(half 0-3, cq 0-3).
// r15: gemm2 epilogue replaced by dots with va=W2*att_src2, vb=W2*att_dst2
// (W2 commutes with the alpha-weighted segment sum -> applied in agg2_gemm).
__global__ __launch_bounds__(256, 8) void agg1_attn(
    const int* __restrict__ rp, const int* __restrict__ csr,
    const float* __restrict__ as, const float* __restrict__ ad,
    const uint4* __restrict__ h1h, const float* __restrict__ b1,
    const float* __restrict__ W2, const float* __restrict__ as2w,
    const float* __restrict__ ad2w, uint4* __restrict__ x1h,
    float* __restrict__ as2, float* __restrict__ ad2, int N) {
  __shared__ float val[32], vbl[32];
  int t = threadIdx.x;
  if (t < 32) {
    float a = 0.f, b = 0.f;
    for (int c = 0; c < 40; c++) {
      float w = W2[t * 40 + c];
      a = fmaf(w, as2w[c], a);
      b = fmaf(w, ad2w[c], b);
    }
    val[t] = a; vbl[t] = b;
  }
  __syncthreads();
  int nl = t >> 4, r = t & 15;
  int half = r >> 2, cq = r & 3;
  int h = cq >> 1;
  int n = blockIdx.x * 16 + nl;
  float acc[8] = {0, 0, 0, 0, 0, 0, 0, 0};
  float ssum = 0.f;
  if (n < N) {
    int p0 = rp[n], p1 = rp[n + 1];
    float adv = ad[n * 2 + h];
    int p = p0 + half;
    // main: 4 independent csr->gather chains in flight per iteration
    for (; p + 12 < p1; p += 16) {
      int sA = csr[p], sB = csr[p + 4], sC = csr[p + 8], sD = csr[p + 12];
      float eA = as[sA * 2 + h] + adv;
      float eB = as[sB * 2 + h] + adv;
      float eC = as[sC * 2 + h] + adv;
      float eD = as[sD * 2 + h] + adv;
      uint4 uA = h1h[(size_t)sA * 4 + cq];
      uint4 uB = h1h[(size_t)sB * 4 + cq];
      uint4 uC = h1h[(size_t)sC * 4 + cq];
      uint4 uD = h1h[(size_t)sD * 4 + cq];
      float xA = __expf(lrelu(eA));
      float xB = __expf(lrelu(eB));
      float xC = __expf(lrelu(eC));
      float xD = __expf(lrelu(eD));
      ssum += (xA + xB) + (xC + xD);
      acc8(acc, xA, uA);
      acc8(acc, xB, uB);
      acc8(acc, xC, uC);
      acc8(acc, xD, uD);
    }
    // tail: <=3 edges, one parallel memory round (clamped + predicated)
    if (p < p1) {
      bool vB = p + 4 < p1, vC = p + 8 < p1;
      int pB = vB ? p + 4 : p;
      int pC = vC ? p + 8 : p;
      int sA = csr[p], sB = csr[pB], sC = csr[pC];
      float eA = as[sA * 2 + h] + adv;
      float eB = as[sB * 2 + h] + adv;
      float eC = as[sC * 2 + h] + adv;
      uint4 uA = h1h[(size_t)sA * 4 + cq];
      uint4 uB = h1h[(size_t)sB * 4 + cq];
      uint4 uC = h1h[(size_t)sC * 4 + cq];
      float xA = __expf(lrelu(eA));
      float xB = vB ? __expf(lrelu(eB)) : 0.f;
      float xC = vC ? __expf(lrelu(eC)) : 0.f;
      ssum += xA + xB + xC;
      acc8(acc, xA, uA);
      acc8(acc, xB, uB);
      acc8(acc, xC, uC);
    }
  }
  // combine 4 split-K halves (lanes r^4, r^8 within the 16-lane node group)
#pragma unroll
  for (int j = 0; j < 8; j++) acc[j] += __shfl_xor(acc[j], 4);
  ssum += __shfl_xor(ssum, 4);
#pragma unroll
  for (int j = 0; j < 8; j++) acc[j] += __shfl_xor(acc[j], 8);
  ssum += __shfl_xor(ssum, 8);
  if (n < N && half == 0) {
    float inv = 1.0f / (ssum + 1e-16f);
    float4 ba = ((const float4*)b1)[cq * 2];
    float4 bb = ((const float4*)b1)[cq * 2 + 1];
    float xv[8];
    xv[0] = fmaxf(fmaf(acc[0], inv, ba.x), 0.f);
    xv[1] = fmaxf(fmaf(acc[1], inv, ba.y), 0.f);
    xv[2] = fmaxf(fmaf(acc[2], inv, ba.z), 0.f);
    xv[3] = fmaxf(fmaf(acc[3], inv, ba.w), 0.f);
    xv[4] = fmaxf(fmaf(acc[4], inv, bb.x), 0.f);
    xv[5] = fmaxf(fmaf(acc[5], inv, bb.y), 0.f);
    xv[6] = fmaxf(fmaf(acc[6], inv, bb.z), 0.f);
    xv[7] = fmaxf(fmaf(acc[7], inv, bb.w), 0.f);
    uint4 u;
    u.x = (unsigned)f2h(xv[0]) | ((unsigned)f2h(xv[1]) << 16);
    u.y = (unsigned)f2h(xv[2]) | ((unsigned)f2h(xv[3]) << 16);
    u.z = (unsigned)f2h(xv[4]) | ((unsigned)f2h(xv[5]) << 16);
    u.w = (unsigned)f2h(xv[6]) | ((unsigned)f2h(xv[7]) << 16);
    x1h[(size_t)n * 4 + cq] = u;
    // attn2 scalars via 32-dots (channel slice cq*8..cq*8+7)
    int ch0 = cq * 8;
    float ss = 0.f, sd = 0.f;
#pragma unroll
    for (int j = 0; j < 8; j++) {
      ss = fmaf(xv[j], val[ch0 + j], ss);
      sd = fmaf(xv[j], vbl[ch0 + j], sd);
    }
    ss += __shfl_xor(ss, 1); sd += __shfl_xor(sd, 1);
    ss += __shfl_xor(ss, 2); sd += __shfl_xor(sd, 2);
    if (cq == 0) { as2[n] = ss; ad2[n] = sd; }
  }
}

// ------- fused softmax+agg over x1 (split-K=4, shfl) + node GEMM 32->40 -----
// block = 16 nodes x 16 threads; gather x1h rows (64B = ONE line per edge);
// epilogue: out[n] = W2^T * aggx[n] + b2 (per-node, LDS GEMM).
__global__ __launch_bounds__(256, 8) void agg2_gemm(
    const int* __restrict__ rp, const int* __restrict__ csr,
    const float* __restrict__ as, const float* __restrict__ ad,
    const uint4* __restrict__ x1h, const float* __restrict__ W2,
    const float* __restrict__ b2, float* __restrict__ outp, int N) {
  __shared__ float Wl[32 * 40];
  __shared__ float xt[16][33];
  __shared__ float hr[16][41];
  int t = threadIdx.x;
  for (int i = t; i < 320; i += 256)
    ((float4*)Wl)[i] = ((const float4*)W2)[i];
  int nl = t >> 4, r = t & 15;
  int half = r >> 2, cq = r & 3;
  int n = blockIdx.x * 16 + nl;
  float acc[8] = {0, 0, 0, 0, 0, 0, 0, 0};
  float ssum = 0.f;
  if (n < N) {
    int p0 = rp[n], p1 = rp[n + 1];
    float adv = ad[n];
    int p = p0 + half;
    for (; p + 12 < p1; p += 16) {
      int sA = csr[p], sB = csr[p + 4], sC = csr[p + 8], sD = csr[p + 12];
      float eA = as[sA] + adv;
      float eB = as[sB] + adv;
      float eC = as[sC] + adv;
      float eD = as[sD] + adv;
      uint4 uA = x1h[(size_t)sA * 4 + cq];
      uint4 uB = x1h[(size_t)sB * 4 + cq];
      uint4 uC = x1h[(size_t)sC * 4 + cq];
      uint4 uD = x1h[(size_t)sD * 4 + cq];
      float xA = __expf(lrelu(eA));
      float xB = __expf(lrelu(eB));
      float xC = __expf(lrelu(eC));
      float xD = __expf(lrelu(eD));
      ssum += (xA + xB) + (xC + xD);
      acc8(acc, xA, uA);
      acc8(acc, xB, uB);
      acc8(acc, xC, uC);
      acc8(acc, xD, uD);
    }
    if (p < p1) {
      bool vB = p + 4 < p1, vC = p + 8 < p1;
      int pB = vB ? p + 4 : p;
      int pC = vC ? p + 8 : p;
      int sA = csr[p], sB = csr[pB], sC = csr[pC];
      float eA = as[sA] + adv;
      float eB = as[sB] + adv;
      float eC = as[sC] + adv;
      uint4 uA = x1h[(size_t)sA * 4 + cq];
      uint4 uB = x1h[(size_t)sB * 4 + cq];
      uint4 uC = x1h[(size_t)sC * 4 + cq];
      float xA = __expf(lrelu(eA));
      float xB = vB ? __expf(lrelu(eB)) : 0.f;
      float xC = vC ? __expf(lrelu(eC)) : 0.f;
      ssum += xA + xB + xC;
      acc8(acc, xA, uA);
      acc8(acc, xB, uB);
      acc8(acc, xC, uC);
    }
  }
#pragma unroll
  for (int j = 0; j < 8; j++) acc[j] += __shfl_xor(acc[j], 4);
  ssum += __shfl_xor(ssum, 4);
#pragma unroll
  for (int j = 0; j < 8; j++) acc[j] += __shfl_xor(acc[j], 8);
  ssum += __shfl_xor(ssum, 8);
  if (n < N && half == 0) {
    float inv = 1.0f / (ssum + 1e-16f);
    int ch0 = cq * 8;
#pragma unroll
    for (int j = 0; j < 8; j++) xt[nl][ch0 + j] = acc[j] * inv;
  }
  __syncthreads();  // covers Wl load + xt writes
  if (n < N && r < 8) {
    float a2[5] = {0, 0, 0, 0, 0};
    int cb = r * 5;
    for (int k = 0; k < 32; k++) {
      float x = xt[nl][k];
#pragma unroll
      for (int c = 0; c < 5; c++)
        a2[c] = fmaf(x, Wl[k * 40 + cb + c], a2[c]);
    }
#pragma unroll
    for (int c = 0; c < 5; c++) hr[nl][cb + c] = a2[c];
  }
  __syncthreads();
  if (n < N && r < 10) {
    const float* s = hr[nl] + r * 4;
    float4 bb = ((const float4*)b2)[r];
    float4 v;
    v.x = s[0] + bb.x; v.y = s[1] + bb.y;
    v.z = s[2] + bb.z; v.w = s[3] + bb.w;
    ((float4*)outp)[(size_t)n * 10 + r] = v;
  }
}

// ---------------- host launcher ----------------
extern "C" void kernel_launch(void* const* d_in, const int* in_sizes, int n_in,
                              void* d_out, int out_size, void* d_ws, size_t ws_size,
                              hipStream_t stream) {
  const float* X    = (const float*)d_in[0];
  const long long* eg64 = (const long long*)d_in[1];
  const int* eg32   = (const int*)d_in[1];
  const float* W1   = (const float*)d_in[3];
  const float* as1w = (const float*)d_in[4];
  const float* ad1w = (const float*)d_in[5];
  const float* b1   = (const float*)d_in[6];
  const float* W2   = (const float*)d_in[7];
  const float* as2w = (const float*)d_in[8];
  const float* ad2w = (const float*)d_in[9];
  const float* b2   = (const float*)d_in[10];
  float* out = (float*)d_out;

  const int N  = in_sizes[0] / 128;
  const int E  = in_sizes[1] / 2;
  const int EN = E + N;
  const int NB2 = (N + CB_SZ - 1) / CB_SZ;
  const int NWG = (EN + SC_CHUNK - 1) / SC_CHUNK;

  char* wbase = (char*)d_ws;
  size_t off = 0;
  auto alloc = [&](size_t bytes) -> void* {
    void* p = wbase + off;
    off += (bytes + 255) & ~(size_t)255;
    return p;
  };

  uint4* h1h = (uint4*)alloc((size_t)N * 64);        // fp16 h1, 64B rows
  // tmp (CSR build scratch) and x1h (fp16 x1 payload) are temporally
  // disjoint: tmp dies at bucket_rp_sort, x1h is born at agg1_attn.
  size_t usz = (size_t)EN * 4;
  if ((size_t)N * 64 > usz) usz = (size_t)N * 64;
  char* uni = (char*)alloc(usz);
  uint4* x1h = (uint4*)uni;
  int*   tmp = (int*)uni;
  float* as1 = (float*)alloc((size_t)N * 2 * 4);
  float* ad1 = (float*)alloc((size_t)N * 2 * 4);
  float* as2 = (float*)alloc((size_t)N * 4);
  float* ad2 = (float*)alloc((size_t)N * 4);
  int* rp     = (int*)alloc((size_t)(N + 1) * 4);
  int* bhist  = (int*)alloc(NBMAX * 4);
  int* bscan  = (int*)alloc((NBMAX + 1) * 4);
  int* gcur   = (int*)alloc(NBMAX * 4);
  int* csr    = (int*)alloc((size_t)EN * 4);
  (void)ws_size; (void)n_in; (void)out_size;

  const int gN = (N + 255) / 256;

  // CSR build: hist -> scan -> sorted scatter (run reservation) -> bucket sort
  hipMemsetAsync(bhist, 0, NBMAX * 4, stream);
  bucket_hist<<<1024, 256, 0, stream>>>(eg64, eg32, E, N, NB2, bhist);
  bucket_scan<<<1, NBMAX, 0, stream>>>(bhist, bscan, gcur, NB2, EN);
  chunk_scatter_sorted<<<NWG, 256, 0, stream>>>(eg64, eg32, E, N, NB2, gcur, tmp);
  bucket_rp_sort<<<NB2, 256, 0, stream>>>(bscan, tmp, rp, csr, N, EN);

  // Layer 1 projection
  gemm1f<<<gN, 256, 0, stream>>>(X, W1, as1w, ad1w, h1h, as1, ad1, N);
  // agg1 + x1 pack + attn2 dots (gemm2 folded out via linearity)
  agg1_attn<<<(N + 15) / 16, 256, 0, stream>>>(rp, csr, as1, ad1, h1h, b1,
                                               W2, as2w, ad2w, x1h, as2, ad2, N);
  // Layer 2: aggregate x1, then per-node GEMM 32->40 + bias -> output
  agg2_gemm<<<(N + 15) / 16, 256, 0, stream>>>(rp, csr, as2, ad2, x1h,
                                               W2, b2, out, N);
}